// Round 3
// baseline (2715.460 us; speedup 1.0000x reference)
//
#include <hip/hip_runtime.h>
#include <hip/hip_bf16.h>
#include <cstdint>

#define A_N   100000   // atoms
#define B_N   200000   // bonds
#define MAXNB 6
#define AFD   133
#define BFD   147
#define HID   512
#define NMOL  8192

typedef __attribute__((ext_vector_type(8))) short bf16x8;
typedef __attribute__((ext_vector_type(4))) float f32x4;

__device__ __forceinline__ unsigned short f2b(float f) {
    unsigned u = __builtin_bit_cast(unsigned, f);
    u += 0x7fffu + ((u >> 16) & 1u);
    return (unsigned short)(u >> 16);
}
__device__ __forceinline__ float blo(unsigned u) { return __builtin_bit_cast(float, u << 16); }
__device__ __forceinline__ float bhi(unsigned u) { return __builtin_bit_cast(float, u & 0xffff0000u); }
__device__ __forceinline__ unsigned pack2f(float a, float b) {
    return (unsigned)f2b(a) | ((unsigned)f2b(b) << 16);
}

// ---------------- diagnostic fallback (ws too small): encode ws_MB into output ----------------
__global__ __launch_bounds__(256) void k_diag(float* __restrict__ out, int n, float val) {
    int i = blockIdx.x * 256 + threadIdx.x;
    if (i < n) out[i] = val;
}

// ---------------- weight transpose + cast (per call; tiny) ----------------
// WiT[n][k]   : k 0..146 = Wi[k][n], 147..159 = 0                         (512 x 160)
// WcatT[n][k] : k 0..511 = Wh[k][n], 512..658 = Wi[k-512][n], 659.. = 0   (512 x 672)
// WoT[n][k]   : k 0..132 = Wo[k][n], 133..159 = 0, 160..671 = Wo[k-27][n] (512 x 672)
__global__ __launch_bounds__(256) void k_weights(
    const float* __restrict__ Wi, const float* __restrict__ Wh, const float* __restrict__ Wo,
    unsigned short* __restrict__ WiT, unsigned short* __restrict__ WcatT, unsigned short* __restrict__ WoT)
{
    int n = blockIdx.x, t = threadIdx.x;
    for (int k = t; k < 160; k += 256)
        WiT[(size_t)n * 160 + k] = (k < BFD) ? f2b(Wi[(size_t)k * HID + n]) : (unsigned short)0;
    for (int k = t; k < 672; k += 256) {
        unsigned short v;
        if (k < HID)             v = f2b(Wh[(size_t)k * HID + n]);
        else if (k < HID + BFD)  v = f2b(Wi[(size_t)(k - HID) * HID + n]);
        else                     v = 0;
        WcatT[(size_t)n * 672 + k] = v;
    }
    for (int k = t; k < 672; k += 256) {
        unsigned short v;
        if (k < AFD)       v = f2b(Wo[(size_t)k * HID + n]);
        else if (k < 160)  v = 0;
        else               v = f2b(Wo[(size_t)(k - 27) * HID + n]);
        WoT[(size_t)n * 672 + k] = v;
    }
}

// ---------------- GEMM 1: msg = relu(f_bonds @ W_i) ----------------
__global__ __launch_bounds__(256) void k_gemm_wi(
    const float* __restrict__ fb, const unsigned short* __restrict__ WiT,
    unsigned short* __restrict__ msg)
{
    __shared__ unsigned short As[128][40];
    __shared__ unsigned short Bs[128][40];
    const int bm = blockIdx.y, bn = blockIdx.x;
    const int row0 = bm * 128, col0 = bn * 128;
    const int tid = threadIdx.x, lane = tid & 63, wid = tid >> 6;
    const int wm = wid >> 1, wn = wid & 1;
    const int r0 = tid >> 2, c0 = tid & 3, r1 = 64 + r0;
    f32x4 acc[4][4] = {};

    const float* pf0 = fb + (size_t)min(row0 + r0, B_N - 1) * BFD;
    const float* pf1 = fb + (size_t)min(row0 + r1, B_N - 1) * BFD;

    for (int k0 = 0; k0 < 160; k0 += 32) {
        __syncthreads();
        {
            int kb = k0 + c0 * 8;
            uint4 q; float v[8];
#pragma unroll
            for (int i = 0; i < 8; i++) { int kg = kb + i; v[i] = (kg < BFD) ? pf0[kg] : 0.f; }
            q.x = pack2f(v[0], v[1]); q.y = pack2f(v[2], v[3]); q.z = pack2f(v[4], v[5]); q.w = pack2f(v[6], v[7]);
            *(uint4*)&As[r0][c0 * 8] = q;
#pragma unroll
            for (int i = 0; i < 8; i++) { int kg = kb + i; v[i] = (kg < BFD) ? pf1[kg] : 0.f; }
            q.x = pack2f(v[0], v[1]); q.y = pack2f(v[2], v[3]); q.z = pack2f(v[4], v[5]); q.w = pack2f(v[6], v[7]);
            *(uint4*)&As[r1][c0 * 8] = q;
        }
        *(uint4*)&Bs[r0][c0 * 8] = *(const uint4*)(WiT + (size_t)(col0 + r0) * 160 + k0 + c0 * 8);
        *(uint4*)&Bs[r1][c0 * 8] = *(const uint4*)(WiT + (size_t)(col0 + r1) * 160 + k0 + c0 * 8);
        __syncthreads();

        bf16x8 af[4], bfr[4];
#pragma unroll
        for (int m = 0; m < 4; m++) af[m] = *(const bf16x8*)&As[wm * 64 + m * 16 + (lane & 15)][(lane >> 4) * 8];
#pragma unroll
        for (int n = 0; n < 4; n++) bfr[n] = *(const bf16x8*)&Bs[wn * 64 + n * 16 + (lane & 15)][(lane >> 4) * 8];
#pragma unroll
        for (int m = 0; m < 4; m++)
#pragma unroll
            for (int n = 0; n < 4; n++)
                acc[m][n] = __builtin_amdgcn_mfma_f32_16x16x32_bf16(af[m], bfr[n], acc[m][n], 0, 0, 0);
    }

#pragma unroll
    for (int m = 0; m < 4; m++) {
        int rbase = row0 + wm * 64 + m * 16 + (lane >> 4) * 4;
#pragma unroll
        for (int n = 0; n < 4; n++) {
            int cg = col0 + wn * 64 + n * 16 + (lane & 15);
#pragma unroll
            for (int r = 0; r < 4; r++) {
                int rg = rbase + r;
                if (rg < B_N) {
                    float v = acc[m][n][r];
                    msg[(size_t)rg * HID + cg] = f2b(v > 0.f ? v : 0.f);
                }
            }
        }
    }
}

// ---------------- delta: D[b] = sum_k msg[a2b[b2a[b]][k]] - msg[b2revb[b]] ----------------
__global__ __launch_bounds__(256) void k_delta(
    const unsigned short* __restrict__ msg, const int* __restrict__ a2b,
    const int* __restrict__ b2a, const int* __restrict__ b2revb,
    unsigned short* __restrict__ D)
{
    int b = blockIdx.x * 4 + (threadIdx.x >> 6);
    if (b >= B_N) return;
    int lane = threadIdx.x & 63;
    const int atom = b2a[b];
    const int rev  = b2revb[b];
    const int* nb = a2b + (size_t)atom * MAXNB;
    float acc[8];
    {
        uint4 v = *(const uint4*)(msg + (size_t)rev * HID + lane * 8);
        acc[0] = -blo(v.x); acc[1] = -bhi(v.x);
        acc[2] = -blo(v.y); acc[3] = -bhi(v.y);
        acc[4] = -blo(v.z); acc[5] = -bhi(v.z);
        acc[6] = -blo(v.w); acc[7] = -bhi(v.w);
    }
#pragma unroll
    for (int k = 0; k < MAXNB; k++) {
        uint4 v = *(const uint4*)(msg + (size_t)nb[k] * HID + lane * 8);
        acc[0] += blo(v.x); acc[1] += bhi(v.x);
        acc[2] += blo(v.y); acc[3] += bhi(v.y);
        acc[4] += blo(v.z); acc[5] += bhi(v.z);
        acc[6] += blo(v.w); acc[7] += bhi(v.w);
    }
    uint4 q;
    q.x = pack2f(acc[0], acc[1]); q.y = pack2f(acc[2], acc[3]);
    q.z = pack2f(acc[4], acc[5]); q.w = pack2f(acc[6], acc[7]);
    *(uint4*)(D + (size_t)b * HID + lane * 8) = q;
}

// ---------------- GEMM 2 (hot): msg = relu([D | f_bonds] @ [W_h; W_i])  (in-place on msg) ----------------
__global__ __launch_bounds__(256) void k_gemm_wh(
    const float* __restrict__ fb, const unsigned short* __restrict__ D,
    const unsigned short* __restrict__ WcatT,
    unsigned short* __restrict__ msg_out)
{
    __shared__ unsigned short As[128][40];
    __shared__ unsigned short Bs[128][40];
    const int bm = blockIdx.y, bn = blockIdx.x;
    const int row0 = bm * 128, col0 = bn * 128;
    const int tid = threadIdx.x, lane = tid & 63, wid = tid >> 6;
    const int wm = wid >> 1, wn = wid & 1;
    const int r0 = tid >> 2, c0 = tid & 3, r1 = 64 + r0;
    f32x4 acc[4][4] = {};

    const int rg0 = min(row0 + r0, B_N - 1), rg1 = min(row0 + r1, B_N - 1);
    const unsigned short* pd0 = D + (size_t)rg0 * HID;
    const unsigned short* pd1 = D + (size_t)rg1 * HID;
    const float* pf0 = fb + (size_t)rg0 * BFD;
    const float* pf1 = fb + (size_t)rg1 * BFD;

    for (int k0 = 0; k0 < 672; k0 += 32) {
        __syncthreads();
        if (k0 < HID) {   // delta region (bf16 pass-through)
            int kb = k0 + c0 * 8;
            *(uint4*)&As[r0][c0 * 8] = *(const uint4*)(pd0 + kb);
            *(uint4*)&As[r1][c0 * 8] = *(const uint4*)(pd1 + kb);
        } else {          // bond-feature region (f32->bf16, zero-pad >=147)
            int kb = (k0 - HID) + c0 * 8;
            uint4 q; float v[8];
#pragma unroll
            for (int i = 0; i < 8; i++) { int kg = kb + i; v[i] = (kg < BFD) ? pf0[kg] : 0.f; }
            q.x = pack2f(v[0], v[1]); q.y = pack2f(v[2], v[3]); q.z = pack2f(v[4], v[5]); q.w = pack2f(v[6], v[7]);
            *(uint4*)&As[r0][c0 * 8] = q;
#pragma unroll
            for (int i = 0; i < 8; i++) { int kg = kb + i; v[i] = (kg < BFD) ? pf1[kg] : 0.f; }
            q.x = pack2f(v[0], v[1]); q.y = pack2f(v[2], v[3]); q.z = pack2f(v[4], v[5]); q.w = pack2f(v[6], v[7]);
            *(uint4*)&As[r1][c0 * 8] = q;
        }
        *(uint4*)&Bs[r0][c0 * 8] = *(const uint4*)(WcatT + (size_t)(col0 + r0) * 672 + k0 + c0 * 8);
        *(uint4*)&Bs[r1][c0 * 8] = *(const uint4*)(WcatT + (size_t)(col0 + r1) * 672 + k0 + c0 * 8);
        __syncthreads();

        bf16x8 af[4], bfr[4];
#pragma unroll
        for (int m = 0; m < 4; m++) af[m] = *(const bf16x8*)&As[wm * 64 + m * 16 + (lane & 15)][(lane >> 4) * 8];
#pragma unroll
        for (int n = 0; n < 4; n++) bfr[n] = *(const bf16x8*)&Bs[wn * 64 + n * 16 + (lane & 15)][(lane >> 4) * 8];
#pragma unroll
        for (int m = 0; m < 4; m++)
#pragma unroll
            for (int n = 0; n < 4; n++)
                acc[m][n] = __builtin_amdgcn_mfma_f32_16x16x32_bf16(af[m], bfr[n], acc[m][n], 0, 0, 0);
    }

#pragma unroll
    for (int m = 0; m < 4; m++) {
        int rbase = row0 + wm * 64 + m * 16 + (lane >> 4) * 4;
#pragma unroll
        for (int n = 0; n < 4; n++) {
            int cg = col0 + wn * 64 + n * 16 + (lane & 15);
#pragma unroll
            for (int r = 0; r < 4; r++) {
                int rg = rbase + r;
                if (rg < B_N) {
                    float v = acc[m][n][r];
                    msg_out[(size_t)rg * HID + cg] = f2b(v > 0.f ? v : 0.f);
                }
            }
        }
    }
}

// ---------------- GEMM 3: atom_hiddens = relu(concat(f_atoms, amsg) @ W_o + b_o) ----------------
__global__ __launch_bounds__(256) void k_gemm_wo(
    const float* __restrict__ fa, const unsigned short* __restrict__ amsg,
    const unsigned short* __restrict__ WoT, const float* __restrict__ bo,
    float* __restrict__ ah)
{
    __shared__ unsigned short As[128][40];
    __shared__ unsigned short Bs[128][40];
    const int bm = blockIdx.y, bn = blockIdx.x;
    const int row0 = bm * 128, col0 = bn * 128;
    const int tid = threadIdx.x, lane = tid & 63, wid = tid >> 6;
    const int wm = wid >> 1, wn = wid & 1;
    const int r0 = tid >> 2, c0 = tid & 3, r1 = 64 + r0;
    f32x4 acc[4][4] = {};

    const int rg0 = min(row0 + r0, A_N - 1), rg1 = min(row0 + r1, A_N - 1);
    const float* pf0 = fa + (size_t)rg0 * AFD;
    const float* pf1 = fa + (size_t)rg1 * AFD;
    const unsigned short* pm0 = amsg + (size_t)rg0 * HID;
    const unsigned short* pm1 = amsg + (size_t)rg1 * HID;

    for (int k0 = 0; k0 < 672; k0 += 32) {
        __syncthreads();
        if (k0 < 160) {
            int kb = k0 + c0 * 8;
            uint4 q; float v[8];
#pragma unroll
            for (int i = 0; i < 8; i++) { int kg = kb + i; v[i] = (kg < AFD) ? pf0[kg] : 0.f; }
            q.x = pack2f(v[0], v[1]); q.y = pack2f(v[2], v[3]); q.z = pack2f(v[4], v[5]); q.w = pack2f(v[6], v[7]);
            *(uint4*)&As[r0][c0 * 8] = q;
#pragma unroll
            for (int i = 0; i < 8; i++) { int kg = kb + i; v[i] = (kg < AFD) ? pf1[kg] : 0.f; }
            q.x = pack2f(v[0], v[1]); q.y = pack2f(v[2], v[3]); q.z = pack2f(v[4], v[5]); q.w = pack2f(v[6], v[7]);
            *(uint4*)&As[r1][c0 * 8] = q;
        } else {
            int kb = (k0 - 160) + c0 * 8;
            *(uint4*)&As[r0][c0 * 8] = *(const uint4*)(pm0 + kb);
            *(uint4*)&As[r1][c0 * 8] = *(const uint4*)(pm1 + kb);
        }
        *(uint4*)&Bs[r0][c0 * 8] = *(const uint4*)(WoT + (size_t)(col0 + r0) * 672 + k0 + c0 * 8);
        *(uint4*)&Bs[r1][c0 * 8] = *(const uint4*)(WoT + (size_t)(col0 + r1) * 672 + k0 + c0 * 8);
        __syncthreads();

        bf16x8 af[4], bfr[4];
#pragma unroll
        for (int m = 0; m < 4; m++) af[m] = *(const bf16x8*)&As[wm * 64 + m * 16 + (lane & 15)][(lane >> 4) * 8];
#pragma unroll
        for (int n = 0; n < 4; n++) bfr[n] = *(const bf16x8*)&Bs[wn * 64 + n * 16 + (lane & 15)][(lane >> 4) * 8];
#pragma unroll
        for (int m = 0; m < 4; m++)
#pragma unroll
            for (int n = 0; n < 4; n++)
                acc[m][n] = __builtin_amdgcn_mfma_f32_16x16x32_bf16(af[m], bfr[n], acc[m][n], 0, 0, 0);
    }

#pragma unroll
    for (int m = 0; m < 4; m++) {
        int rbase = row0 + wm * 64 + m * 16 + (lane >> 4) * 4;
#pragma unroll
        for (int n = 0; n < 4; n++) {
            int cg = col0 + wn * 64 + n * 16 + (lane & 15);
            float bias = bo[cg];
#pragma unroll
            for (int r = 0; r < 4; r++) {
                int rg = rbase + r;
                if (rg < A_N) {
                    float v = acc[m][n][r] + bias;
                    ah[(size_t)rg * HID + cg] = v > 0.f ? v : 0.f;
                }
            }
        }
    }
}

// ---------------- final gather-sum: amsg[a] = sum_k msg[a2b[a][k]] ----------------
__global__ __launch_bounds__(256) void k_gather(
    const unsigned short* __restrict__ msg, const int* __restrict__ a2b,
    unsigned short* __restrict__ amsg)
{
    int g = blockIdx.x * 4 + (threadIdx.x >> 6);
    if (g >= A_N) return;
    int lane = threadIdx.x & 63;
    const int* nb = a2b + (size_t)g * MAXNB;
    float acc[8] = {};
#pragma unroll
    for (int k = 0; k < MAXNB; k++) {
        uint4 v = *(const uint4*)(msg + (size_t)nb[k] * HID + lane * 8);
        acc[0] += blo(v.x); acc[1] += bhi(v.x);
        acc[2] += blo(v.y); acc[3] += bhi(v.y);
        acc[4] += blo(v.z); acc[5] += bhi(v.z);
        acc[6] += blo(v.w); acc[7] += bhi(v.w);
    }
    uint4 q;
    q.x = pack2f(acc[0], acc[1]); q.y = pack2f(acc[2], acc[3]);
    q.z = pack2f(acc[4], acc[5]); q.w = pack2f(acc[6], acc[7]);
    *(uint4*)(amsg + (size_t)g * HID + lane * 8) = q;
}

// ---------------- per-molecule mean (atom_to_mol is sorted) ----------------
__global__ __launch_bounds__(256) void k_segmean(
    const float* __restrict__ ah, const int* __restrict__ a2m, float* __restrict__ out)
{
    int mol = blockIdx.x, t = threadIdx.x;
    int lo, hi;
    { int l = 0, r = A_N; while (l < r) { int m = (l + r) >> 1; if (a2m[m] < mol) l = m + 1; else r = m; } lo = l; }
    { int l = lo, r = A_N; while (l < r) { int m = (l + r) >> 1; if (a2m[m] < mol + 1) l = m + 1; else r = m; } hi = l; }
    float s0 = 0.f, s1 = 0.f;
    for (int a = lo; a < hi; a++) {
        s0 += ah[(size_t)a * HID + t];
        s1 += ah[(size_t)a * HID + 256 + t];
    }
    int c = hi - lo;
    float inv = c > 0 ? 1.0f / (float)c : 0.f;
    out[(size_t)mol * HID + t] = s0 * inv;
    out[(size_t)mol * HID + 256 + t] = s1 * inv;
}

extern "C" void kernel_launch(void* const* d_in, const int* in_sizes, int n_in,
                              void* d_out, int out_size, void* d_ws, size_t ws_size,
                              hipStream_t stream)
{
    const float* f_atoms = (const float*)d_in[0];
    const float* f_bonds = (const float*)d_in[1];
    const float* W_i     = (const float*)d_in[2];
    const float* W_h     = (const float*)d_in[3];
    const float* W_o     = (const float*)d_in[4];
    const float* b_o     = (const float*)d_in[5];
    const int*   a2b     = (const int*)d_in[6];
    const int*   b2a     = (const int*)d_in[7];
    const int*   b2revb  = (const int*)d_in[8];
    const int*   a2m     = (const int*)d_in[9];

    // workspace layout: 411,140,096 bytes total (fits the 432 MiB budget)
    const size_t OFF_MSG  = 0;              // bf16 [B,H] 204,800,000 ; later f32 ah [A,H]
    const size_t OFF_D    = 204800000;      // bf16 [B,H] 204,800,000 ; later bf16 amsg [A,H]
    const size_t OFF_WIT  = 409600000;      // 163,840
    const size_t OFF_WCAT = 409763840;      // 688,128
    const size_t OFF_WOT  = 410451968;      // 688,128
    const size_t REQUIRED = 411140096;

    if (ws_size < REQUIRED) {
        float val = -(10000.0f + (float)(ws_size >> 20));
        k_diag<<<dim3((out_size + 255) / 256), dim3(256), 0, stream>>>((float*)d_out, out_size, val);
        return;
    }

    char* w = (char*)d_ws;
    unsigned short* msg  = (unsigned short*)(w + OFF_MSG);
    unsigned short* D    = (unsigned short*)(w + OFF_D);
    unsigned short* amsg = (unsigned short*)(w + OFF_D);   // aliases D (dead after loop)
    unsigned short* WiT  = (unsigned short*)(w + OFF_WIT);
    unsigned short* Wcat = (unsigned short*)(w + OFF_WCAT);
    unsigned short* WoT  = (unsigned short*)(w + OFF_WOT);
    float* ah = (float*)(w + OFF_MSG);                     // aliases msg (dead after final gather)

    k_weights<<<dim3(512), dim3(256), 0, stream>>>(W_i, W_h, W_o, WiT, Wcat, WoT);
    k_gemm_wi<<<dim3(4, 1563), dim3(256), 0, stream>>>(f_bonds, WiT, msg);
    for (int it = 0; it < 4; ++it) {
        k_delta<<<dim3(50000), dim3(256), 0, stream>>>(msg, a2b, b2a, b2revb, D);
        k_gemm_wh<<<dim3(4, 1563), dim3(256), 0, stream>>>(f_bonds, D, Wcat, msg);
    }
    k_gather<<<dim3(25000), dim3(256), 0, stream>>>(msg, a2b, amsg);
    k_gemm_wo<<<dim3(4, 782), dim3(256), 0, stream>>>(f_atoms, amsg, WoT, b_o, ah);
    k_segmean<<<dim3(NMOL), dim3(256), 0, stream>>>(ah, a2m, (float*)d_out);
}